// Round 16
// baseline (311.077 us; speedup 1.0000x reference)
//
#include <hip/hip_runtime.h>

typedef __attribute__((ext_vector_type(8))) short short8;
typedef __attribute__((ext_vector_type(4))) float f32x4;

#define NB 8
#define NP 64
#define NS 256
#define ND 256
#define NH (NB * NP * NS)
#define BK 32
#define TSTR 40    // LDS tile row stride (shorts): 80 B = 5x16 (b128-aligned); bank step 20 -> free 2-way alias

// round-to-nearest-even fp32 -> bf16 bits
__device__ __forceinline__ unsigned short f2bf(float f) {
    unsigned int u = __float_as_uint(f);
    u = (u + 0x7FFFu + ((u >> 16) & 1u)) >> 16;
    return (unsigned short)u;
}

// K0: zero the atomic accumulators (red, Sx, Sxx contiguous = 3*NH floats).
// (kernel instead of hipMemsetAsync: avoids any graph-capture tripwire)
__global__ __launch_bounds__(256) void k0_zero(float* __restrict__ buf)
{
    const size_t i = (size_t)blockIdx.x * 1024 + threadIdx.x;
    #pragma unroll
    for (int k = 0; k < 4; ++k)
        reinterpret_cast<f32x4*>(buf)[i + (size_t)k * 256] = f32x4{0.f, 0.f, 0.f, 0.f};
}

// K1 reformulated: red_s = (1/16) x_s . (W X)_s  — a STANDARD GEMM
// Z = W[p] (M=256 s) x X^T (K=256 t, N=2048 (b,d)) with fused epilogue.
// Why: r0-r14 proved the monolithic kernel (135 KB LDS -> 1 block/CU, 16 waves
// in barrier lockstep) is structurally stuck at 82 us with every pipe <15% busy
// (warm-L3 replay = same 82 us at FETCH 1.5 MB). This shape needs only 20 KB
// LDS/block -> 4 INDEPENDENT blocks/CU; overlap across blocks, not waves.
// Block = (p, mt, nt): C-tile 128(s) x 128(d) for one b; 256 thr = 4 waves,
// each wave one 64x64 quadrant (4x4 16x16x32 MFMAs, K-loop BK=32).
// Epilogue: read x fp32 tile, emit red (w folded into Z), Sx, Sxx via atomicAdd.
__global__ __launch_bounds__(256, 4) void k1_wx(
    const float* __restrict__ x, const float* __restrict__ w,
    float* __restrict__ red, float* __restrict__ Sx, float* __restrict__ Sxx)
{
    __shared__ unsigned short Al[128 * TSTR];   // A tile: w[s-local][k]   10.2 KB
    __shared__ unsigned short Bl[128 * TSTR];   // B tile: x^T[d-local][k] 10.2 KB

    const int t    = threadIdx.x;
    const int lane = t & 63;
    const int wq   = t >> 6;                    // 0..3
    const int qm   = wq >> 1;                   // M-half of quadrant
    const int qn   = wq & 1;                    // N-half
    const int bid  = blockIdx.x;
    const int p    = bid >> 5;                  // 64 p's x 32 tiles
    const int mt   = (bid >> 4) & 1;            // M-tile (s 0..127 / 128..255)
    const int nt   = bid & 15;                  // N-tile: b = nt>>1, d-half = nt&1
    const int b    = nt >> 1;
    const int d0   = (nt & 1) * 128;
    const int Ms   = mt * 128;

    const float* wp = w + (size_t)p * (NS * NS) + (size_t)Ms * NS;  // 128 x 256 panel
    const float* xb = x + (size_t)(b * NP + p) * (NS * ND);

    // staging assignments
    const int ar  = t >> 1;                     // A row (s-local)
    const int ak0 = (t & 1) * 16;               // A k-offset
    const int bn  = t & 127;                    // B row (d-local)
    const int bk0 = (t >> 7) * 16;              // B k-offset

    const int qd = lane >> 4;
    const int c  = lane & 15;

    f32x4 acc[4][4] = {};

    for (int k0 = 0; k0 < NS; k0 += BK) {
        // ---- stage A: w[p, Ms+ar, k0+ak0..+15] -> Al[ar][ak0..] (bf16) ----
        {
            const float* src = wp + (size_t)ar * NS + k0 + ak0;
            #pragma unroll
            for (int h = 0; h < 2; ++h) {
                f32x4 v0 = *reinterpret_cast<const f32x4*>(src + 8 * h);
                f32x4 v1 = *reinterpret_cast<const f32x4*>(src + 8 * h + 4);
                short8 s8;
                s8[0] = (short)f2bf(v0.x); s8[1] = (short)f2bf(v0.y);
                s8[2] = (short)f2bf(v0.z); s8[3] = (short)f2bf(v0.w);
                s8[4] = (short)f2bf(v1.x); s8[5] = (short)f2bf(v1.y);
                s8[6] = (short)f2bf(v1.z); s8[7] = (short)f2bf(v1.w);
                *reinterpret_cast<short8*>(&Al[ar * TSTR + ak0 + 8 * h]) = s8;
            }
        }
        // ---- stage B transposed: x[b,p, k0+bk0+j, d0+bn] -> Bl[bn][bk0+j] ----
        // loads coalesced across the 128-thread n-group (512 B per j)
        {
            const float* src = xb + (size_t)(k0 + bk0) * ND + d0 + bn;
            #pragma unroll
            for (int h = 0; h < 2; ++h) {
                short8 s8;
                #pragma unroll
                for (int j = 0; j < 8; ++j)
                    s8[j] = (short)f2bf(src[(size_t)(8 * h + j) * ND]);
                *reinterpret_cast<short8*>(&Bl[bn * TSTR + bk0 + 8 * h]) = s8;
            }
        }
        __syncthreads();

        // ---- quadrant GEMM: 16 MFMAs, k-depth 32 (qd picks 8-elem slice) ----
        {
            const int kof = qd * 8;
            short8 afr[4], bfr[4];
            #pragma unroll
            for (int i = 0; i < 4; ++i)
                afr[i] = *reinterpret_cast<const short8*>(
                    &Al[(64 * qm + 16 * i + c) * TSTR + kof]);
            #pragma unroll
            for (int j = 0; j < 4; ++j)
                bfr[j] = *reinterpret_cast<const short8*>(
                    &Bl[(64 * qn + 16 * j + c) * TSTR + kof]);
            #pragma unroll
            for (int i = 0; i < 4; ++i)
                #pragma unroll
                for (int j = 0; j < 4; ++j)
                    acc[i][j] = __builtin_amdgcn_mfma_f32_16x16x32_bf16(
                        afr[i], bfr[j], acc[i][j], 0, 0, 0);
        }
        __syncthreads();
    }

    // ---- fused epilogue: C layout col=c (d-local), row=4qd+r (s-local).
    // z[s][n] dotted with exact fp32 x; also Sx=sum x, Sxx=sum x^2 over the
    // same 64-d slice this wave owns. 16-lane reduce, lane c==0 atomics. ----
    const float* xe = xb + (size_t)Ms * ND + d0;
    const size_t rowbase = (size_t)(b * NP + p) * NS + Ms;
    #pragma unroll
    for (int i = 0; i < 4; ++i) {
        #pragma unroll
        for (int r = 0; r < 4; ++r) {
            const int sl = 64 * qm + 16 * i + 4 * qd + r;   // s-local in [0,128)
            const float* xrow = xe + (size_t)sl * ND + 64 * qn + c;
            const float x0 = xrow[0],  x1 = xrow[16];
            const float x2 = xrow[32], x3 = xrow[48];
            float pr = acc[i][0][r] * x0 + acc[i][1][r] * x1
                     + acc[i][2][r] * x2 + acc[i][3][r] * x3;
            float sx = (x0 + x1) + (x2 + x3);
            float sq = (x0 * x0 + x1 * x1) + (x2 * x2 + x3 * x3);
            #pragma unroll
            for (int off = 1; off < 16; off <<= 1) {
                pr += __shfl_xor(pr, off, 64);
                sx += __shfl_xor(sx, off, 64);
                sq += __shfl_xor(sq, off, 64);
            }
            if (c == 0) {
                atomicAdd(&red[rowbase + sl], pr * 0.0625f);
                atomicAdd(&Sx [rowbase + sl], sx);
                atomicAdd(&Sxx[rowbase + sl], sq);
            }
        }
    }
}

// K2: per-channel BN stats -> scale/bias (unchanged)
__global__ __launch_bounds__(256) void k2_stats(
    const float* __restrict__ red, const float* __restrict__ Sx,
    const float* __restrict__ Sxx, const float* __restrict__ gamma,
    const float* __restrict__ beta, float* __restrict__ sb)
{
    __shared__ float l1[256], l2[256];
    const int p = blockIdx.x;
    const int t = threadIdx.x;
    float sy = 0.f, syy = 0.f;
    for (int n = t; n < NB * NS; n += 256) {
        int bb = n >> 8, s = n & 255;
        size_t idx = (size_t)(bb * NP + p) * NS + s;
        float r = red[idx], a = Sx[idx], q = Sxx[idx];
        sy  += a + 256.f * r;
        syy += q + 2.f * r * a + 256.f * r * r;
    }
    l1[t] = sy; l2[t] = syy;
    __syncthreads();
    for (int off = 128; off > 0; off >>= 1) {
        if (t < off) { l1[t] += l1[t + off]; l2[t] += l2[t + off]; }
        __syncthreads();
    }
    if (t == 0) {
        const float invN = 1.f / (float)(NB * NS * ND);
        float mean = l1[0] * invN;
        float var  = l2[0] * invN - mean * mean;
        float sc   = gamma[p] * rsqrtf(var + 1e-5f);
        sb[p]      = sc;
        sb[64 + p] = beta[p] - mean * sc;
    }
}

// K3: out = (x + red) * scale[p] + bias[p]; plain stores (r14: nt was null)
__global__ __launch_bounds__(256) void k3_norm(
    const float* __restrict__ x, const float* __restrict__ red,
    const float* __restrict__ sb, float* __restrict__ out)
{
    const size_t f0 = (size_t)blockIdx.x * 1024 + threadIdx.x;
    #pragma unroll
    for (int k = 0; k < 4; ++k) {
        const size_t f = f0 + (size_t)k * 256;            // float4 index
        f32x4 v = reinterpret_cast<const f32x4*>(x)[f];
        const float r  = red[f >> 6];                     // row = elem>>8 = f>>6
        const int   pp = (int)((f >> 14) & 63);
        v = (v + r) * sb[pp] + sb[64 + pp];
        reinterpret_cast<f32x4*>(out)[f] = v;
    }
}

extern "C" void kernel_launch(void* const* d_in, const int* in_sizes, int n_in,
                              void* d_out, int out_size, void* d_ws, size_t ws_size,
                              hipStream_t stream)
{
    const float* x     = (const float*)d_in[0];
    const float* w     = (const float*)d_in[1];
    const float* gamma = (const float*)d_in[2];
    const float* beta  = (const float*)d_in[3];
    float* out = (float*)d_out;

    float* red = (float*)d_ws;                  // NH floats
    float* Sx  = red + (size_t)NH;              // NH
    float* Sxx = Sx  + (size_t)NH;              // NH
    float* sb  = Sxx + (size_t)NH;              // 128 floats (scale, bias)

    // zero the atomic accumulators: 3*NH floats = 393216 f32x4 / 1024 per block
    hipLaunchKernelGGL(k0_zero, dim3((3 * NH) / (4 * 1024)), dim3(256), 0, stream,
                       red);

    // grid: 64 p x 2 M-tiles x 16 N-tiles = 2048 blocks of 256 thr
    hipLaunchKernelGGL(k1_wx, dim3(NP * 32), dim3(256), 0, stream,
                       x, w, red, Sx, Sxx);
    hipLaunchKernelGGL(k2_stats, dim3(NP), dim3(256), 0, stream,
                       red, Sx, Sxx, gamma, beta, sb);
    hipLaunchKernelGGL(k3_norm, dim3((NB * NP * NS * ND) / (16 * 256)), dim3(256),
                       0, stream, x, red, sb, out);
}